// Round 1
// baseline (11267.406 us; speedup 1.0000x reference)
//
#include <hip/hip_runtime.h>
#include <math.h>

// ---------------------------------------------------------------------------
// TannerGNN: h = relu(x@W_in+b); 3x { per-edge 2-layer MLP msgs (per-type W),
// segment-sum into dst, GRU update }; readout = relu(h@Wr1+br1)@Wr2+br2.
// N_NODES=50000, N_EDGES=400000, H=128, L=3, T=2, FEAT=4, N_DATA=40000.
// ---------------------------------------------------------------------------

#define H 128
#define FEAT 4
#define TE 64     // edges per message tile

// ---------------- input projection: h = relu(x @ W_in + b_in) --------------
__global__ __launch_bounds__(256) void k_input(
    const float* __restrict__ x, const float* __restrict__ Win,
    const float* __restrict__ bin, float* __restrict__ h, int n_nodes)
{
    int idx = blockIdx.x * 256 + threadIdx.x;
    if (idx >= n_nodes * H) return;
    int n = idx >> 7, j = idx & 127;
    float acc = bin[j];
#pragma unroll
    for (int f = 0; f < FEAT; f++)
        acc += x[n * FEAT + f] * Win[f * H + j];
    h[idx] = fmaxf(acc, 0.f);
}

// ---------------- bucket edges by type (T=2) -------------------------------
// ctrl[0..1]=counts, ctrl[2..3]=scatter cursors (all zeroed by memset).
__global__ __launch_bounds__(256) void k_count(
    const int* __restrict__ et, int* __restrict__ ctrl, int n_edges)
{
    int i = blockIdx.x * 256 + threadIdx.x;
    if (i < n_edges) atomicAdd(&ctrl[et[i]], 1);
}

__global__ __launch_bounds__(256) void k_scatter(
    const int* __restrict__ et, int* __restrict__ ctrl,
    int* __restrict__ bucket, int n_edges)
{
    int i = blockIdx.x * 256 + threadIdx.x;
    if (i < n_edges) {
        int t = et[i];
        int pos = atomicAdd(&ctrl[2 + t], 1);
        int base = t ? ctrl[0] : 0;
        bucket[base + pos] = i;
    }
}

// ---------------- fused message kernel -------------------------------------
// One block = 64 edges of a single type.
// Phase A: hidden = relu(cat @ W1 + b1), cat = [h[src], h[dst]] (K=256)
// Phase B: msg = hidden @ W2 + b2 (K=128)
// Phase C: atomicAdd msg into agg[dst].
// Thread t: feature group j4 = 4*(t%32); edge set e = (t/32) + 8*i, i<8.
__global__ __launch_bounds__(256) void k_msg(
    const float* __restrict__ h,
    const int* __restrict__ bucket, const int* __restrict__ ctrl,
    const int* __restrict__ src, const int* __restrict__ dst,
    const float* __restrict__ W1l, const float* __restrict__ b1l,
    const float* __restrict__ W2l, const float* __restrict__ b2l,
    float* __restrict__ agg)
{
    const int t = blockIdx.y;            // edge type
    const int cnt = ctrl[t];
    const int base = t ? ctrl[0] : 0;
    const int start = blockIdx.x * TE;
    if (start >= cnt) return;
    const int nE = min(TE, cnt - start);

    const float* __restrict__ W1 = W1l + t * 2 * H * H;   // (256,128)
    const float* __restrict__ b1 = b1l + t * H;
    const float* __restrict__ W2 = W2l + t * H * H;       // (128,128)
    const float* __restrict__ b2 = b2l + t * H;

    __shared__ float sW[16][H];        // weight k-chunk (8 KB)
    __shared__ float sCat[TE][16];     // cat k-chunk (4 KB)
    __shared__ float sHid[TE][H];      // hidden tile (32 KB)
    __shared__ int sSrc[TE], sDst[TE];

    const int tid = threadIdx.x;
    if (tid < TE) {
        int i = start + tid;
        int e = bucket[base + (i < cnt ? i : start)];  // clamp duplicates
        sSrc[tid] = src[e];
        sDst[tid] = dst[e];
    }

    const int jg = tid & 31;
    const int j4 = jg * 4;
    const int eg = tid >> 5;

    float acc[8][4];
#pragma unroll
    for (int i = 0; i < 8; i++)
#pragma unroll
        for (int c = 0; c < 4; c++) acc[i][c] = 0.f;

    // ---- Phase A: K = 256 in 16 chunks of 16 ----
    for (int kc = 0; kc < 16; kc++) {
        __syncthreads();
        {   // stage cat chunk: thread -> (edge tid/4, 4 cols)
            int e = tid >> 2, q = (tid & 3) * 4;
            int row = (kc < 8) ? sSrc[e] : sDst[e];
            int col = (kc & 7) * 16 + q;
            *(float4*)&sCat[e][q] =
                *(const float4*)(h + (size_t)row * H + col);
        }
#pragma unroll
        for (int v = 0; v < 2; v++) {   // stage W1 chunk (16x128)
            int f4 = tid + 256 * v;
            int r = f4 >> 5, c4 = (f4 & 31) * 4;
            *(float4*)&sW[r][c4] =
                *(const float4*)(W1 + (size_t)(kc * 16 + r) * H + c4);
        }
        __syncthreads();
#pragma unroll
        for (int k4 = 0; k4 < 4; k4++) {
            float4 w0 = *(float4*)&sW[k4 * 4 + 0][j4];
            float4 w1v = *(float4*)&sW[k4 * 4 + 1][j4];
            float4 w2v = *(float4*)&sW[k4 * 4 + 2][j4];
            float4 w3v = *(float4*)&sW[k4 * 4 + 3][j4];
#pragma unroll
            for (int i = 0; i < 8; i++) {
                float4 cv = *(float4*)&sCat[eg + 8 * i][k4 * 4];
                acc[i][0] += cv.x * w0.x + cv.y * w1v.x + cv.z * w2v.x + cv.w * w3v.x;
                acc[i][1] += cv.x * w0.y + cv.y * w1v.y + cv.z * w2v.y + cv.w * w3v.y;
                acc[i][2] += cv.x * w0.z + cv.y * w1v.z + cv.z * w2v.z + cv.w * w3v.z;
                acc[i][3] += cv.x * w0.w + cv.y * w1v.w + cv.z * w2v.w + cv.w * w3v.w;
            }
        }
    }

    // bias + relu -> sHid
    {
        float4 bb = *(const float4*)(b1 + j4);
#pragma unroll
        for (int i = 0; i < 8; i++) {
            int e = eg + 8 * i;
            float4 hv;
            hv.x = fmaxf(acc[i][0] + bb.x, 0.f);
            hv.y = fmaxf(acc[i][1] + bb.y, 0.f);
            hv.z = fmaxf(acc[i][2] + bb.z, 0.f);
            hv.w = fmaxf(acc[i][3] + bb.w, 0.f);
            *(float4*)&sHid[e][j4] = hv;
        }
    }

    // ---- Phase B: msg = hidden @ W2 + b2, K = 128 in 8 chunks of 16 ----
    float acc2[8][4];
    {
        float4 bb = *(const float4*)(b2 + j4);
#pragma unroll
        for (int i = 0; i < 8; i++) {
            acc2[i][0] = bb.x; acc2[i][1] = bb.y;
            acc2[i][2] = bb.z; acc2[i][3] = bb.w;
        }
    }
    for (int kc = 0; kc < 8; kc++) {
        __syncthreads();   // also orders sHid writes before first reads
#pragma unroll
        for (int v = 0; v < 2; v++) {   // stage W2 chunk
            int f4 = tid + 256 * v;
            int r = f4 >> 5, c4 = (f4 & 31) * 4;
            *(float4*)&sW[r][c4] =
                *(const float4*)(W2 + (size_t)(kc * 16 + r) * H + c4);
        }
        __syncthreads();
#pragma unroll
        for (int k4 = 0; k4 < 4; k4++) {
            float4 w0 = *(float4*)&sW[k4 * 4 + 0][j4];
            float4 w1v = *(float4*)&sW[k4 * 4 + 1][j4];
            float4 w2v = *(float4*)&sW[k4 * 4 + 2][j4];
            float4 w3v = *(float4*)&sW[k4 * 4 + 3][j4];
#pragma unroll
            for (int i = 0; i < 8; i++) {
                float4 cv = *(float4*)&sHid[eg + 8 * i][kc * 16 + k4 * 4];
                acc2[i][0] += cv.x * w0.x + cv.y * w1v.x + cv.z * w2v.x + cv.w * w3v.x;
                acc2[i][1] += cv.x * w0.y + cv.y * w1v.y + cv.z * w2v.y + cv.w * w3v.y;
                acc2[i][2] += cv.x * w0.z + cv.y * w1v.z + cv.z * w2v.z + cv.w * w3v.z;
                acc2[i][3] += cv.x * w0.w + cv.y * w1v.w + cv.z * w2v.w + cv.w * w3v.w;
            }
        }
    }

    // ---- Phase C: scatter-add into agg[dst] ----
#pragma unroll
    for (int i = 0; i < 8; i++) {
        int e = eg + 8 * i;
        if (e < nE) {
            float* dp = agg + (size_t)sDst[e] * H + j4;
            atomicAdd(dp + 0, acc2[i][0]);
            atomicAdd(dp + 1, acc2[i][1]);
            atomicAdd(dp + 2, acc2[i][2]);
            atomicAdd(dp + 3, acc2[i][3]);
        }
    }
}

// ---------------- GRU cell (8 nodes per block, in-place h update) ----------
__global__ __launch_bounds__(256) void k_gru(
    float* __restrict__ h, const float* __restrict__ agg,
    const float* __restrict__ Wih, const float* __restrict__ bih,
    const float* __restrict__ Whh, const float* __restrict__ bhh,
    int n_nodes)
{
    const int nb = blockIdx.x * 8;
    const int tid = threadIdx.x;
    const int j = tid & 127;
    const int g = tid >> 7;           // 0/1

    __shared__ float sA[8][H], sH[8][H];
    {
        int e = tid >> 5, q = (tid & 31) * 4;
        int n = nb + e;
        if (n < n_nodes) {
            *(float4*)&sA[e][q] = *(const float4*)(agg + (size_t)n * H + q);
            *(float4*)&sH[e][q] = *(const float4*)(h + (size_t)n * H + q);
        }
    }
    __syncthreads();

    float a_r[4] = {0, 0, 0, 0}, a_z[4] = {0, 0, 0, 0}, a_n[4] = {0, 0, 0, 0};
    float g_r[4] = {0, 0, 0, 0}, g_z[4] = {0, 0, 0, 0}, g_n[4] = {0, 0, 0, 0};

    for (int k = 0; k < H; k++) {
        float wr = Wih[k * 384 + j];
        float wz = Wih[k * 384 + 128 + j];
        float wn = Wih[k * 384 + 256 + j];
        float vr = Whh[k * 384 + j];
        float vz = Whh[k * 384 + 128 + j];
        float vn = Whh[k * 384 + 256 + j];
#pragma unroll
        for (int i = 0; i < 4; i++) {
            int e = g + 2 * i;
            float a = sA[e][k], hh = sH[e][k];
            a_r[i] += a * wr;  a_z[i] += a * wz;  a_n[i] += a * wn;
            g_r[i] += hh * vr; g_z[i] += hh * vz; g_n[i] += hh * vn;
        }
    }

    float br_ = bih[j], bz_ = bih[128 + j], bn_ = bih[256 + j];
    float cr = bhh[j], cz = bhh[128 + j], cn = bhh[256 + j];
#pragma unroll
    for (int i = 0; i < 4; i++) {
        int e = g + 2 * i;
        int n = nb + e;
        if (n < n_nodes) {
            float r = 1.f / (1.f + expf(-(a_r[i] + br_ + g_r[i] + cr)));
            float z = 1.f / (1.f + expf(-(a_z[i] + bz_ + g_z[i] + cz)));
            float nn = tanhf(a_n[i] + bn_ + r * (g_n[i] + cn));
            h[(size_t)n * H + j] = (1.f - z) * nn + z * sH[e][j];
        }
    }
}

// ---------------- readout: out = relu(h@Wr1+br1) @ Wr2 + br2 ---------------
__global__ __launch_bounds__(128) void k_readout(
    const float* __restrict__ h, const float* __restrict__ Wr1,
    const float* __restrict__ br1, const float* __restrict__ Wr2,
    const float* __restrict__ br2, float* __restrict__ out, int n_out)
{
    const int n = blockIdx.x;
    if (n >= n_out) return;
    __shared__ float sh[H];
    __shared__ float wsum[2];
    const int j = threadIdx.x;
    sh[j] = h[(size_t)n * H + j];
    __syncthreads();
    float acc = br1[j];
    for (int k = 0; k < H; k++)
        acc += sh[k] * Wr1[k * H + j];
    float val = fmaxf(acc, 0.f) * Wr2[j];
#pragma unroll
    for (int off = 32; off > 0; off >>= 1)
        val += __shfl_down(val, off, 64);
    if ((j & 63) == 0) wsum[j >> 6] = val;
    __syncthreads();
    if (j == 0) out[n] = wsum[0] + wsum[1] + br2[0];
}

// ---------------------------------------------------------------------------
extern "C" void kernel_launch(void* const* d_in, const int* in_sizes, int n_in,
                              void* d_out, int out_size, void* d_ws, size_t ws_size,
                              hipStream_t stream)
{
    const float* x      = (const float*)d_in[0];
    const int*   eidx   = (const int*)d_in[1];
    const int*   etype  = (const int*)d_in[2];
    // d_in[3] = n_data (device scalar); we use out_size instead (host-known)
    const float* Win    = (const float*)d_in[4];
    const float* bin    = (const float*)d_in[5];
    const float* W1     = (const float*)d_in[6];   // (3,2,256,128)
    const float* b1     = (const float*)d_in[7];   // (3,2,128)
    const float* W2     = (const float*)d_in[8];   // (3,2,128,128)
    const float* b2     = (const float*)d_in[9];   // (3,2,128)
    const float* Wih    = (const float*)d_in[10];  // (3,128,384)
    const float* bih    = (const float*)d_in[11];  // (3,384)
    const float* Whh    = (const float*)d_in[12];  // (3,128,384)
    const float* bhh    = (const float*)d_in[13];  // (3,384)
    const float* Wr1    = (const float*)d_in[14];  // (128,128)
    const float* br1    = (const float*)d_in[15];  // (128)
    const float* Wr2    = (const float*)d_in[16];  // (128,1)
    const float* br2    = (const float*)d_in[17];  // (1)

    const int n_nodes = in_sizes[0] / FEAT;
    const int n_edges = in_sizes[1] / 2;
    const int L = 3;

    const int* src = eidx;
    const int* dst = eidx + n_edges;

    // workspace carve-up
    float* h   = (float*)d_ws;
    float* agg = h + (size_t)n_nodes * H;
    int* bucket = (int*)(agg + (size_t)n_nodes * H);
    int* ctrl   = bucket + n_edges;          // 4 ints

    hipMemsetAsync(ctrl, 0, 4 * sizeof(int), stream);

    k_input<<<(n_nodes * H + 255) / 256, 256, 0, stream>>>(x, Win, bin, h, n_nodes);

    const int eb = (n_edges + 255) / 256;
    k_count<<<eb, 256, 0, stream>>>(etype, ctrl, n_edges);
    k_scatter<<<eb, 256, 0, stream>>>(etype, ctrl, bucket, n_edges);

    const dim3 mgrid((n_edges + TE - 1) / TE, 2);
    for (int l = 0; l < L; l++) {
        hipMemsetAsync(agg, 0, (size_t)n_nodes * H * sizeof(float), stream);
        k_msg<<<mgrid, 256, 0, stream>>>(
            h, bucket, ctrl, src, dst,
            W1 + (size_t)l * 2 * 2 * H * H, b1 + (size_t)l * 2 * H,
            W2 + (size_t)l * 2 * H * H,     b2 + (size_t)l * 2 * H,
            agg);
        k_gru<<<(n_nodes + 7) / 8, 256, 0, stream>>>(
            h, agg,
            Wih + (size_t)l * H * 384, bih + (size_t)l * 384,
            Whh + (size_t)l * H * 384, bhh + (size_t)l * 384,
            n_nodes);
    }

    k_readout<<<out_size, 128, 0, stream>>>(h, Wr1, br1, Wr2, br2,
                                            (float*)d_out, out_size);
}

// Round 2
// 2188.101 us; speedup vs baseline: 5.1494x; 5.1494x over previous
//
#include <hip/hip_runtime.h>
#include <math.h>

// ---------------------------------------------------------------------------
// TannerGNN. Round 2: bf16 MFMA message GEMMs, aggregated-atomic scatter.
// N_NODES=50000, N_EDGES=400000, H=128, L=3, T=2, FEAT=4, N_DATA=40000.
// ---------------------------------------------------------------------------

#define H 128
#define TE 64          // edges per message tile
#define CATS 264       // sCat row stride in bf16 (256 + 8 pad -> 2-way banks)
#define HS  136        // sHid row stride in bf16 (128 + 8 pad)
#define FEAT 4

typedef __bf16 bf16x8 __attribute__((ext_vector_type(8)));
typedef float  f32x4  __attribute__((ext_vector_type(4)));

// ---------------- input projection: h = relu(x @ W_in + b_in) --------------
__global__ __launch_bounds__(256) void k_input(
    const float* __restrict__ x, const float* __restrict__ Win,
    const float* __restrict__ bin, float* __restrict__ h,
    __bf16* __restrict__ hb, int n_nodes)
{
    int idx = blockIdx.x * 256 + threadIdx.x;
    if (idx >= n_nodes * H) return;
    int n = idx >> 7, j = idx & 127;
    float acc = bin[j];
#pragma unroll
    for (int f = 0; f < FEAT; f++)
        acc += x[n * FEAT + f] * Win[f * H + j];
    float v = fmaxf(acc, 0.f);
    h[idx] = v;
    hb[idx] = (__bf16)v;
}

// ---------------- weight conversion: bf16, transposed to [n][k] ------------
// Wt1[lt][n][k] = W1[lt][k][n]  (lt = l*2+t, k<256, n<128)
// Wt2[lt][n][k] = W2[lt][k][n]  (k<128, n<128)
__global__ __launch_bounds__(256) void k_wconv(
    const float* __restrict__ W1, const float* __restrict__ W2,
    __bf16* __restrict__ Wt1, __bf16* __restrict__ Wt2)
{
    int idx = blockIdx.x * 256 + threadIdx.x;
    const int tot1 = 6 * 256 * 128;
    const int tot2 = 6 * 128 * 128;
    if (idx < tot1) {
        int lt = idx / (256 * 128), rem = idx % (256 * 128);
        int k = rem >> 7, n = rem & 127;
        Wt1[((size_t)lt * 128 + n) * 256 + k] = (__bf16)W1[idx];
    } else if (idx < tot1 + tot2) {
        int j = idx - tot1;
        int lt = j / (128 * 128), rem = j % (128 * 128);
        int k = rem >> 7, n = rem & 127;
        Wt2[((size_t)lt * 128 + n) * 128 + k] = (__bf16)W2[j];
    }
}

// ---------------- bucket edges by type, aggregated atomics -----------------
// ctrl[0]=count type0, ctrl[1]=count type1 (zeroed before launch).
// type0 bucket grows from 0; type1 bucket grows down from n_edges-1.
__global__ __launch_bounds__(256) void k_scatter(
    const int* __restrict__ et, int* __restrict__ ctrl,
    int* __restrict__ bucket, int n_edges)
{
    __shared__ int wc0[4], wc1[4], bb0, bb1;
    int i = blockIdx.x * 256 + threadIdx.x;
    int lane = threadIdx.x & 63;
    int w = threadIdx.x >> 6;
    int t = (i < n_edges) ? et[i] : -1;
    unsigned long long m0 = __ballot(t == 0);
    unsigned long long m1 = __ballot(t == 1);
    unsigned long long ltm = lane ? (~0ull >> (64 - lane)) : 0ull;
    int r0 = __popcll(m0 & ltm), r1 = __popcll(m1 & ltm);
    if (lane == 0) { wc0[w] = __popcll(m0); wc1[w] = __popcll(m1); }
    __syncthreads();
    if (threadIdx.x == 0) {
        int s0 = 0, s1 = 0;
#pragma unroll
        for (int k = 0; k < 4; k++) {
            int c = wc0[k]; wc0[k] = s0; s0 += c;
            c = wc1[k]; wc1[k] = s1; s1 += c;
        }
        bb0 = atomicAdd(&ctrl[0], s0);
        bb1 = atomicAdd(&ctrl[1], s1);
    }
    __syncthreads();
    if (t == 0)      bucket[bb0 + wc0[w] + r0] = i;
    else if (t == 1) bucket[n_edges - 1 - (bb1 + wc1[w] + r1)] = i;
}

// ---------------- fused MFMA message kernel --------------------------------
// Block = 64 edges of one type, 4 waves; wave w owns edges [16w,16w+16).
// Phase A: hid = relu(cat @ W1 + b1)  (M=16/wave, N=128, K=256, bf16 MFMA)
// Phase B: msg = hid @ W2 + b2        (K=128)
// Phase C: fp32 atomicAdd into agg[dst].
// B-fragments read straight from global (L2-resident transposed bf16 weights).
// sHid aliases the wave's own sCat region (each wave only touches its rows).
__global__ __launch_bounds__(256) void k_msg(
    const __bf16* __restrict__ hb,
    const int* __restrict__ bucket, const int* __restrict__ ctrl,
    const int* __restrict__ src, const int* __restrict__ dst,
    const __bf16* __restrict__ Wt1l, const float* __restrict__ b1l,
    const __bf16* __restrict__ Wt2l, const float* __restrict__ b2l,
    float* __restrict__ agg, int n_edges)
{
    const int t = blockIdx.y;
    const int cnt = ctrl[t];
    const int base = t ? (n_edges - cnt) : 0;
    const int start = blockIdx.x * TE;
    if (start >= cnt) return;
    const int nE = min(TE, cnt - start);

    const __bf16* __restrict__ Wt1 = Wt1l + (size_t)t * 128 * 256;
    const __bf16* __restrict__ Wt2 = Wt2l + (size_t)t * 128 * 128;
    const float*  __restrict__ b1  = b1l + t * H;
    const float*  __restrict__ b2  = b2l + t * H;

    __shared__ __bf16 sCat[TE * CATS];     // 33792 B
    __shared__ int sSrc[TE], sDst[TE];

    const int tid  = threadIdx.x;
    const int lane = tid & 63;
    const int w    = tid >> 6;
    const int r    = lane & 15;
    const int quad = lane >> 4;

    if (tid < TE) {
        int i = start + tid;
        int e = bucket[base + (i < cnt ? i : start)];
        sSrc[tid] = src[e];
        sDst[tid] = dst[e];
    }
    __syncthreads();

    {   // stage cat tile: 128 rows (edge,half) x 128 bf16; 2 threads/row
        int row_id = tid >> 1;
        int e = row_id >> 1, half = row_id & 1;
        int node = half ? sDst[e] : sSrc[e];
        const __bf16* gp = hb + (size_t)node * H;
        __bf16* lp = sCat + e * CATS + half * H;
        int cbase = (tid & 1) * 8;
#pragma unroll
        for (int i = 0; i < 8; i++) {
            int c = cbase + i;
            *(f32x4*)(lp + c * 8) = *(const f32x4*)(gp + c * 8);
        }
    }
    __syncthreads();

    // ---- Phase A: K=256 in 8 MFMA k-steps ----
    f32x4 acc[8];
#pragma unroll
    for (int ct = 0; ct < 8; ct++) acc[ct] = (f32x4){0.f, 0.f, 0.f, 0.f};

    const __bf16* sA = sCat + (size_t)w * 16 * CATS;
#pragma unroll
    for (int kc = 0; kc < 8; kc++) {
        bf16x8 a = *(const bf16x8*)(sA + r * CATS + kc * 32 + quad * 8);
#pragma unroll
        for (int ct = 0; ct < 8; ct++) {
            bf16x8 b = *(const bf16x8*)(Wt1 + (size_t)(ct * 16 + r) * 256 + kc * 32 + quad * 8);
            acc[ct] = __builtin_amdgcn_mfma_f32_16x16x32_bf16(a, b, acc[ct], 0, 0, 0);
        }
    }

    // epilogue A: bias + relu -> bf16 -> sHid (aliases this wave's sCat rows)
    __bf16* sHid = sCat + (size_t)w * 16 * CATS;   // stride HS
#pragma unroll
    for (int ct = 0; ct < 8; ct++) {
        int col = ct * 16 + r;
        float bb = b1[col];
#pragma unroll
        for (int g = 0; g < 4; g++) {
            float v = fmaxf(acc[ct][g] + bb, 0.f);
            sHid[(quad * 4 + g) * HS + col] = (__bf16)v;
        }
    }

    // ---- Phase B: K=128 in 4 MFMA k-steps ----
    f32x4 acc2[8];
#pragma unroll
    for (int ct = 0; ct < 8; ct++) acc2[ct] = (f32x4){0.f, 0.f, 0.f, 0.f};
#pragma unroll
    for (int kc = 0; kc < 4; kc++) {
        bf16x8 a = *(const bf16x8*)(sHid + r * HS + kc * 32 + quad * 8);
#pragma unroll
        for (int ct = 0; ct < 8; ct++) {
            bf16x8 b = *(const bf16x8*)(Wt2 + (size_t)(ct * 16 + r) * 128 + kc * 32 + quad * 8);
            acc2[ct] = __builtin_amdgcn_mfma_f32_16x16x32_bf16(a, b, acc2[ct], 0, 0, 0);
        }
    }

    // ---- Phase C: scatter-add ----
#pragma unroll
    for (int ct = 0; ct < 8; ct++) {
        int col = ct * 16 + r;
        float bb = b2[col];
#pragma unroll
        for (int g = 0; g < 4; g++) {
            int e = w * 16 + quad * 4 + g;
            if (e < nE)
                atomicAdd(agg + (size_t)sDst[e] * H + col, acc2[ct][g] + bb);
        }
    }
}

// ---------------- GRU cell (8 nodes per block, in-place h update) ----------
__global__ __launch_bounds__(256) void k_gru(
    float* __restrict__ h, __bf16* __restrict__ hb,
    const float* __restrict__ agg,
    const float* __restrict__ Wih, const float* __restrict__ bih,
    const float* __restrict__ Whh, const float* __restrict__ bhh,
    int n_nodes)
{
    const int nb = blockIdx.x * 8;
    const int tid = threadIdx.x;
    const int j = tid & 127;
    const int g = tid >> 7;           // 0/1

    __shared__ float sA[8][H], sH[8][H];
    {
        int e = tid >> 5, q = (tid & 31) * 4;
        int n = nb + e;
        if (n < n_nodes) {
            *(float4*)&sA[e][q] = *(const float4*)(agg + (size_t)n * H + q);
            *(float4*)&sH[e][q] = *(const float4*)(h + (size_t)n * H + q);
        }
    }
    __syncthreads();

    float a_r[4] = {0, 0, 0, 0}, a_z[4] = {0, 0, 0, 0}, a_n[4] = {0, 0, 0, 0};
    float g_r[4] = {0, 0, 0, 0}, g_z[4] = {0, 0, 0, 0}, g_n[4] = {0, 0, 0, 0};

    for (int k = 0; k < H; k++) {
        float wr = Wih[k * 384 + j];
        float wz = Wih[k * 384 + 128 + j];
        float wn = Wih[k * 384 + 256 + j];
        float vr = Whh[k * 384 + j];
        float vz = Whh[k * 384 + 128 + j];
        float vn = Whh[k * 384 + 256 + j];
#pragma unroll
        for (int i = 0; i < 4; i++) {
            int e = g + 2 * i;
            float a = sA[e][k], hh = sH[e][k];
            a_r[i] += a * wr;  a_z[i] += a * wz;  a_n[i] += a * wn;
            g_r[i] += hh * vr; g_z[i] += hh * vz; g_n[i] += hh * vn;
        }
    }

    float br_ = bih[j], bz_ = bih[128 + j], bn_ = bih[256 + j];
    float cr = bhh[j], cz = bhh[128 + j], cn = bhh[256 + j];
#pragma unroll
    for (int i = 0; i < 4; i++) {
        int e = g + 2 * i;
        int n = nb + e;
        if (n < n_nodes) {
            float rr = 1.f / (1.f + expf(-(a_r[i] + br_ + g_r[i] + cr)));
            float zz = 1.f / (1.f + expf(-(a_z[i] + bz_ + g_z[i] + cz)));
            float nn = tanhf(a_n[i] + bn_ + rr * (g_n[i] + cn));
            float out = (1.f - zz) * nn + zz * sH[e][j];
            h[(size_t)n * H + j] = out;
            hb[(size_t)n * H + j] = (__bf16)out;
        }
    }
}

// ---------------- readout: out = relu(h@Wr1+br1) @ Wr2 + br2 ---------------
__global__ __launch_bounds__(128) void k_readout(
    const float* __restrict__ h, const float* __restrict__ Wr1,
    const float* __restrict__ br1, const float* __restrict__ Wr2,
    const float* __restrict__ br2, float* __restrict__ out, int n_out)
{
    const int n = blockIdx.x;
    if (n >= n_out) return;
    __shared__ float sh[H];
    __shared__ float wsum[2];
    const int j = threadIdx.x;
    sh[j] = h[(size_t)n * H + j];
    __syncthreads();
    float acc = br1[j];
    for (int k = 0; k < H; k++)
        acc += sh[k] * Wr1[k * H + j];
    float val = fmaxf(acc, 0.f) * Wr2[j];
#pragma unroll
    for (int off = 32; off > 0; off >>= 1)
        val += __shfl_down(val, off, 64);
    if ((j & 63) == 0) wsum[j >> 6] = val;
    __syncthreads();
    if (j == 0) out[n] = wsum[0] + wsum[1] + br2[0];
}

// ---------------------------------------------------------------------------
extern "C" void kernel_launch(void* const* d_in, const int* in_sizes, int n_in,
                              void* d_out, int out_size, void* d_ws, size_t ws_size,
                              hipStream_t stream)
{
    const float* x      = (const float*)d_in[0];
    const int*   eidx   = (const int*)d_in[1];
    const int*   etype  = (const int*)d_in[2];
    const float* Win    = (const float*)d_in[4];
    const float* bin    = (const float*)d_in[5];
    const float* W1     = (const float*)d_in[6];   // (3,2,256,128)
    const float* b1     = (const float*)d_in[7];   // (3,2,128)
    const float* W2     = (const float*)d_in[8];   // (3,2,128,128)
    const float* b2     = (const float*)d_in[9];   // (3,2,128)
    const float* Wih    = (const float*)d_in[10];  // (3,128,384)
    const float* bih    = (const float*)d_in[11];  // (3,384)
    const float* Whh    = (const float*)d_in[12];  // (3,128,384)
    const float* bhh    = (const float*)d_in[13];  // (3,384)
    const float* Wr1    = (const float*)d_in[14];
    const float* br1    = (const float*)d_in[15];
    const float* Wr2    = (const float*)d_in[16];
    const float* br2    = (const float*)d_in[17];

    const int n_nodes = in_sizes[0] / FEAT;
    const int n_edges = in_sizes[1] / 2;
    const int L = 3;
    const size_t nh = (size_t)n_nodes * H;

    const int* src = eidx;
    const int* dst = eidx + n_edges;

    // workspace carve-up
    float*  h    = (float*)d_ws;                    // 25.6 MB
    float*  agg  = h + nh;                          // 25.6 MB
    __bf16* hb   = (__bf16*)(agg + nh);             // 12.8 MB
    __bf16* Wt1  = hb + nh;                         // 6*128*256 bf16
    __bf16* Wt2  = Wt1 + 6 * 128 * 256;             // 6*128*128 bf16
    int* bucket  = (int*)(Wt2 + 6 * 128 * 128);
    int* ctrl    = bucket + n_edges;                // 2 ints

    hipMemsetAsync(ctrl, 0, 2 * sizeof(int), stream);

    k_wconv<<<(6 * 256 * 128 + 6 * 128 * 128 + 255) / 256, 256, 0, stream>>>(
        W1, W2, Wt1, Wt2);
    k_input<<<((int)nh + 255) / 256, 256, 0, stream>>>(x, Win, bin, h, hb, n_nodes);
    k_scatter<<<(n_edges + 255) / 256, 256, 0, stream>>>(etype, ctrl, bucket, n_edges);

    const dim3 mgrid((n_edges + TE - 1) / TE, 2);
    for (int l = 0; l < L; l++) {
        hipMemsetAsync(agg, 0, nh * sizeof(float), stream);
        k_msg<<<mgrid, 256, 0, stream>>>(
            hb, bucket, ctrl, src, dst,
            Wt1 + (size_t)l * 2 * 128 * 256, b1 + (size_t)l * 2 * H,
            Wt2 + (size_t)l * 2 * 128 * 128, b2 + (size_t)l * 2 * H,
            agg, n_edges);
        k_gru<<<(n_nodes + 7) / 8, 256, 0, stream>>>(
            h, hb, agg,
            Wih + (size_t)l * H * 384, bih + (size_t)l * 384,
            Whh + (size_t)l * H * 384, bhh + (size_t)l * 384,
            n_nodes);
    }

    k_readout<<<out_size, 128, 0, stream>>>(h, Wr1, br1, Wr2, br2,
                                            (float*)d_out, out_size);
}

// Round 3
// 1886.330 us; speedup vs baseline: 5.9732x; 1.1600x over previous
//
#include <hip/hip_runtime.h>
#include <math.h>

// ---------------------------------------------------------------------------
// TannerGNN. Round 3: (type,dst) counting-sorted edges, LDS segmented
// reduction before atomics, improved GRU/readout weight reuse.
// N_NODES=50000, N_EDGES=400000, H=128, L=3, T=2, FEAT=4, N_DATA=40000.
// ---------------------------------------------------------------------------

#define H 128
#define TE 64          // edges per message tile
#define CATS 264       // sCat row stride in bf16 (256 + 8 pad)
#define HS  136        // sHid row stride in bf16 (128 + 8 pad)
#define MS  132        // sMsg row stride in f32  (128 + 4 pad)
#define FEAT 4

typedef __bf16 bf16x8 __attribute__((ext_vector_type(8)));
typedef float  f32x4  __attribute__((ext_vector_type(4)));

// ---------------- input projection: h = relu(x @ W_in + b_in) --------------
__global__ __launch_bounds__(256) void k_input(
    const float* __restrict__ x, const float* __restrict__ Win,
    const float* __restrict__ bin, float* __restrict__ h,
    __bf16* __restrict__ hb, int n_nodes)
{
    int idx = blockIdx.x * 256 + threadIdx.x;
    if (idx >= n_nodes * H) return;
    int n = idx >> 7, j = idx & 127;
    float acc = bin[j];
#pragma unroll
    for (int f = 0; f < FEAT; f++)
        acc += x[n * FEAT + f] * Win[f * H + j];
    float v = fmaxf(acc, 0.f);
    h[idx] = v;
    hb[idx] = (__bf16)v;
}

// ---------------- weight conversion: bf16, transposed to [n][k] ------------
__global__ __launch_bounds__(256) void k_wconv(
    const float* __restrict__ W1, const float* __restrict__ W2,
    __bf16* __restrict__ Wt1, __bf16* __restrict__ Wt2)
{
    int idx = blockIdx.x * 256 + threadIdx.x;
    const int tot1 = 6 * 256 * 128;
    const int tot2 = 6 * 128 * 128;
    if (idx < tot1) {
        int lt = idx / (256 * 128), rem = idx % (256 * 128);
        int k = rem >> 7, n = rem & 127;
        Wt1[((size_t)lt * 128 + n) * 256 + k] = (__bf16)W1[idx];
    } else if (idx < tot1 + tot2) {
        int j = idx - tot1;
        int lt = j / (128 * 128), rem = j % (128 * 128);
        int k = rem >> 7, n = rem & 127;
        Wt2[((size_t)lt * 128 + n) * 128 + k] = (__bf16)W2[j];
    }
}

// ---------------- counting sort by key = type*nn + dst ---------------------
__global__ __launch_bounds__(256) void k_hist(
    const int* __restrict__ et, const int* __restrict__ dst,
    int* __restrict__ cnt, int n_edges, int nn)
{
    int i = blockIdx.x * 256 + threadIdx.x;
    if (i < n_edges) atomicAdd(&cnt[et[i] * nn + dst[i]], 1);
}

// single-block exclusive scan over n=2*nn counters; offs[n] = total
__global__ __launch_bounds__(1024) void k_scan(
    const int* __restrict__ cnt, int* __restrict__ offs, int n)
{
    __shared__ int sW[16];
    __shared__ int sBase;
    if (threadIdx.x == 0) sBase = 0;
    __syncthreads();
    int lane = threadIdx.x & 63, w = threadIdx.x >> 6;
    for (int c = 0; c < n; c += 1024) {
        int idx = c + threadIdx.x;
        int v = (idx < n) ? cnt[idx] : 0;
        int orig = v;
#pragma unroll
        for (int off = 1; off < 64; off <<= 1) {
            int t = __shfl_up(v, off, 64);
            if (lane >= off) v += t;
        }
        if (lane == 63) sW[w] = v;
        __syncthreads();
        if (w == 0 && lane < 16) {
            int x = sW[lane];
#pragma unroll
            for (int off = 1; off < 16; off <<= 1) {
                int t = __shfl_up(x, off, 64);
                if (lane >= off) x += t;
            }
            sW[lane] = x;
        }
        __syncthreads();
        int wbase = w ? sW[w - 1] : 0;
        int base = sBase;
        if (idx < n) offs[idx] = base + wbase + v - orig;
        __syncthreads();
        if (threadIdx.x == 0) sBase = base + sW[15];
        __syncthreads();
    }
    if (threadIdx.x == 0) offs[n] = sBase;
}

__global__ __launch_bounds__(256) void k_place(
    const int* __restrict__ et, const int* __restrict__ dst,
    const int* __restrict__ offs, int* __restrict__ cur,
    int* __restrict__ bucket, int n_edges, int nn)
{
    int i = blockIdx.x * 256 + threadIdx.x;
    if (i < n_edges) {
        int key = et[i] * nn + dst[i];
        int p = atomicAdd(&cur[key], 1);
        bucket[offs[key] + p] = i;
    }
}

// ---------------- fused MFMA message kernel --------------------------------
// Block = 64 dst-sorted edges of one type, 4 waves; wave w owns 16 edges.
// A: hid = relu(cat @ W1 + b1); B: msg = hid @ W2 + b2;
// C: LDS segmented reduction over dst runs, then few atomics into agg.
__global__ __launch_bounds__(256) void k_msg(
    const __bf16* __restrict__ hb,
    const int* __restrict__ bucket, const int* __restrict__ offs,
    const int* __restrict__ src, const int* __restrict__ dst,
    const __bf16* __restrict__ Wt1l, const float* __restrict__ b1l,
    const __bf16* __restrict__ Wt2l, const float* __restrict__ b2l,
    float* __restrict__ agg, int n_edges, int nn)
{
    const int t = blockIdx.y;
    const int c0 = offs[nn];                 // total type-0 edges
    const int cnt = t ? (n_edges - c0) : c0;
    const int base = t ? c0 : 0;
    const int start = blockIdx.x * TE;
    if (start >= cnt) return;

    const __bf16* __restrict__ Wt1 = Wt1l + (size_t)t * 128 * 256;
    const __bf16* __restrict__ Wt2 = Wt2l + (size_t)t * 128 * 128;
    const float*  __restrict__ b1  = b1l + t * H;
    const float*  __restrict__ b2  = b2l + t * H;

    __shared__ float sBuf[TE * MS];          // 33792 B, aliased below
    __bf16* sCat = (__bf16*)sBuf;            // TE rows x CATS bf16
    float*  sMsg = sBuf;                     // TE rows x MS f32
    __shared__ int sSrc[TE], sDstN[TE], sDstV[TE];

    const int tid  = threadIdx.x;
    const int lane = tid & 63;
    const int w    = tid >> 6;
    const int r    = lane & 15;
    const int quad = lane >> 4;

    if (tid < TE) {
        int i = start + tid;
        int e = bucket[base + (i < cnt ? i : start)];
        sSrc[tid]  = src[e];
        sDstN[tid] = dst[e];
        sDstV[tid] = (i < cnt) ? dst[e] : -1;
    }
    __syncthreads();

    {   // stage cat tile: 128 rows (edge,half) x 128 bf16; 2 threads/row
        int row_id = tid >> 1;
        int e = row_id >> 1, half = row_id & 1;
        int node = half ? sDstN[e] : sSrc[e];
        const __bf16* gp = hb + (size_t)node * H;
        __bf16* lp = sCat + e * CATS + half * H;
        int cbase = (tid & 1) * 8;
#pragma unroll
        for (int i = 0; i < 8; i++) {
            int c = cbase + i;
            *(f32x4*)(lp + c * 8) = *(const f32x4*)(gp + c * 8);
        }
    }
    __syncthreads();

    // ---- Phase A: K=256 in 8 MFMA k-steps ----
    f32x4 acc[8];
#pragma unroll
    for (int ct = 0; ct < 8; ct++) acc[ct] = (f32x4){0.f, 0.f, 0.f, 0.f};

    const __bf16* sA = sCat + (size_t)w * 16 * CATS;
#pragma unroll
    for (int kc = 0; kc < 8; kc++) {
        bf16x8 a = *(const bf16x8*)(sA + r * CATS + kc * 32 + quad * 8);
#pragma unroll
        for (int ct = 0; ct < 8; ct++) {
            bf16x8 b = *(const bf16x8*)(Wt1 + (size_t)(ct * 16 + r) * 256 + kc * 32 + quad * 8);
            acc[ct] = __builtin_amdgcn_mfma_f32_16x16x32_bf16(a, b, acc[ct], 0, 0, 0);
        }
    }

    // epilogue A: bias + relu -> bf16 -> sHid (aliases this wave's sCat rows)
    __bf16* sHid = sCat + (size_t)w * 16 * CATS;   // stride HS
#pragma unroll
    for (int ct = 0; ct < 8; ct++) {
        int col = ct * 16 + r;
        float bb = b1[col];
#pragma unroll
        for (int g = 0; g < 4; g++) {
            float v = fmaxf(acc[ct][g] + bb, 0.f);
            sHid[(quad * 4 + g) * HS + col] = (__bf16)v;
        }
    }

    // ---- Phase B: K=128 in 4 MFMA k-steps ----
    f32x4 acc2[8];
#pragma unroll
    for (int ct = 0; ct < 8; ct++) acc2[ct] = (f32x4){0.f, 0.f, 0.f, 0.f};
#pragma unroll
    for (int kc = 0; kc < 4; kc++) {
        bf16x8 a = *(const bf16x8*)(sHid + r * HS + kc * 32 + quad * 8);
#pragma unroll
        for (int ct = 0; ct < 8; ct++) {
            bf16x8 b = *(const bf16x8*)(Wt2 + (size_t)(ct * 16 + r) * 128 + kc * 32 + quad * 8);
            acc2[ct] = __builtin_amdgcn_mfma_f32_16x16x32_bf16(a, b, acc2[ct], 0, 0, 0);
        }
    }

    // ---- Phase C: msgs (+bias) -> sMsg (own wave rows), then segmented sum
    #pragma unroll
    for (int ct = 0; ct < 8; ct++) {
        int col = ct * 16 + r;
        float bb = b2[col];
#pragma unroll
        for (int g = 0; g < 4; g++) {
            int e = w * 16 + quad * 4 + g;
            sMsg[e * MS + col] = acc2[ct][g] + bb;
        }
    }
    __syncthreads();

    {   // dst-sorted rows: accumulate runs, one atomic per run per column
        int j = tid & 127, hf = tid >> 7;
        int r0 = hf * 32;
        float run = 0.f; int curd = -1;
        for (int e = r0; e < r0 + 32; e++) {
            int d = sDstV[e];
            float v = sMsg[e * MS + j];
            if (d != curd) {
                if (curd >= 0) atomicAdd(agg + (size_t)curd * H + j, run);
                run = 0.f; curd = d;
            }
            if (d >= 0) run += v;
        }
        if (curd >= 0) atomicAdd(agg + (size_t)curd * H + j, run);
    }
}

// ---------------- GRU cell (16 nodes per block, in-place h update) ---------
__global__ __launch_bounds__(256) void k_gru(
    float* __restrict__ h, __bf16* __restrict__ hb,
    const float* __restrict__ agg,
    const float* __restrict__ Wih, const float* __restrict__ bih,
    const float* __restrict__ Whh, const float* __restrict__ bhh,
    int n_nodes)
{
    const int nb = blockIdx.x * 16;
    const int tid = threadIdx.x;

    __shared__ float sA[16][H], sH[16][H];
    {
        int e = tid >> 4, q = (tid & 15) * 8;
        int n = nb + e;
        if (n < n_nodes) {
            *(float4*)&sA[e][q]     = *(const float4*)(agg + (size_t)n * H + q);
            *(float4*)&sA[e][q + 4] = *(const float4*)(agg + (size_t)n * H + q + 4);
            *(float4*)&sH[e][q]     = *(const float4*)(h + (size_t)n * H + q);
            *(float4*)&sH[e][q + 4] = *(const float4*)(h + (size_t)n * H + q + 4);
        }
    }
    __syncthreads();

    const int j = tid & 127;
    const int g = tid >> 7;           // 0/1

    float ar[8] = {0,0,0,0,0,0,0,0}, az[8] = {0,0,0,0,0,0,0,0},
          an[8] = {0,0,0,0,0,0,0,0}, gr[8] = {0,0,0,0,0,0,0,0},
          gz[8] = {0,0,0,0,0,0,0,0}, gn[8] = {0,0,0,0,0,0,0,0};

    for (int k = 0; k < H; k++) {
        float wr = Wih[k * 384 + j];
        float wz = Wih[k * 384 + 128 + j];
        float wn = Wih[k * 384 + 256 + j];
        float vr = Whh[k * 384 + j];
        float vz = Whh[k * 384 + 128 + j];
        float vn = Whh[k * 384 + 256 + j];
#pragma unroll
        for (int i = 0; i < 8; i++) {
            int e = g + 2 * i;
            float a = sA[e][k], hh = sH[e][k];
            ar[i] += a * wr;  az[i] += a * wz;  an[i] += a * wn;
            gr[i] += hh * vr; gz[i] += hh * vz; gn[i] += hh * vn;
        }
    }

    float br_ = bih[j], bz_ = bih[128 + j], bn_ = bih[256 + j];
    float cr = bhh[j], cz = bhh[128 + j], cn = bhh[256 + j];
#pragma unroll
    for (int i = 0; i < 8; i++) {
        int e = g + 2 * i;
        int n = nb + e;
        if (n < n_nodes) {
            float rr = 1.f / (1.f + expf(-(ar[i] + br_ + gr[i] + cr)));
            float zz = 1.f / (1.f + expf(-(az[i] + bz_ + gz[i] + cz)));
            float nv = tanhf(an[i] + bn_ + rr * (gn[i] + cn));
            float out = (1.f - zz) * nv + zz * sH[e][j];
            h[(size_t)n * H + j] = out;
            hb[(size_t)n * H + j] = (__bf16)out;
        }
    }
}

// ---------------- readout: out = relu(h@Wr1+br1) @ Wr2 + br2 ---------------
__global__ __launch_bounds__(128) void k_readout(
    const float* __restrict__ h, const float* __restrict__ Wr1,
    const float* __restrict__ br1, const float* __restrict__ Wr2,
    const float* __restrict__ br2, float* __restrict__ out, int n_out)
{
    const int n0 = blockIdx.x * 8;
    const int tid = threadIdx.x;     // 128
    __shared__ float sh[8][H];
    __shared__ float sRed[2][8];
    {
        int e = tid >> 4, q = (tid & 15) * 8;
        int n = n0 + e;
        if (n < n_out) {
            const float* hp = h + (size_t)n * H + q;
            *(float4*)&sh[e][q]     = *(const float4*)hp;
            *(float4*)&sh[e][q + 4] = *(const float4*)(hp + 4);
        }
    }
    __syncthreads();

    const int j = tid;
    float bb = br1[j];
    float acc[8];
#pragma unroll
    for (int e = 0; e < 8; e++) acc[e] = bb;
    for (int k = 0; k < H; k++) {
        float wv = Wr1[k * H + j];
#pragma unroll
        for (int e = 0; e < 8; e++) acc[e] += sh[e][k] * wv;
    }
    float w2 = Wr2[j];
    int lane = tid & 63, w = tid >> 6;
#pragma unroll
    for (int e = 0; e < 8; e++) {
        float val = fmaxf(acc[e], 0.f) * w2;
#pragma unroll
        for (int off = 32; off > 0; off >>= 1)
            val += __shfl_down(val, off, 64);
        if (lane == 0) sRed[w][e] = val;
    }
    __syncthreads();
    if (tid < 8 && n0 + tid < n_out)
        out[n0 + tid] = sRed[0][tid] + sRed[1][tid] + br2[0];
}

// ---------------------------------------------------------------------------
extern "C" void kernel_launch(void* const* d_in, const int* in_sizes, int n_in,
                              void* d_out, int out_size, void* d_ws, size_t ws_size,
                              hipStream_t stream)
{
    const float* x      = (const float*)d_in[0];
    const int*   eidx   = (const int*)d_in[1];
    const int*   etype  = (const int*)d_in[2];
    const float* Win    = (const float*)d_in[4];
    const float* bin    = (const float*)d_in[5];
    const float* W1     = (const float*)d_in[6];   // (3,2,256,128)
    const float* b1     = (const float*)d_in[7];   // (3,2,128)
    const float* W2     = (const float*)d_in[8];   // (3,2,128,128)
    const float* b2     = (const float*)d_in[9];   // (3,2,128)
    const float* Wih    = (const float*)d_in[10];  // (3,128,384)
    const float* bih    = (const float*)d_in[11];  // (3,384)
    const float* Whh    = (const float*)d_in[12];  // (3,128,384)
    const float* bhh    = (const float*)d_in[13];  // (3,384)
    const float* Wr1    = (const float*)d_in[14];
    const float* br1    = (const float*)d_in[15];
    const float* Wr2    = (const float*)d_in[16];
    const float* br2    = (const float*)d_in[17];

    const int n_nodes = in_sizes[0] / FEAT;
    const int n_edges = in_sizes[1] / 2;
    const int L = 3;
    const size_t nh = (size_t)n_nodes * H;

    const int* src = eidx;
    const int* dst = eidx + n_edges;

    // workspace carve-up
    float*  h    = (float*)d_ws;                    // 25.6 MB
    float*  agg  = h + nh;                          // 25.6 MB
    __bf16* hb   = (__bf16*)(agg + nh);             // 12.8 MB
    __bf16* Wt1  = hb + nh;
    __bf16* Wt2  = Wt1 + 6 * 128 * 256;
    int* bucket  = (int*)(Wt2 + 6 * 128 * 128);     // n_edges
    int* cnt     = bucket + n_edges;                // 2*nn
    int* cur     = cnt + 2 * n_nodes;               // 2*nn
    int* offs    = cur + 2 * n_nodes;               // 2*nn + 1

    hipMemsetAsync(cnt, 0, (size_t)2 * n_nodes * sizeof(int), stream);
    hipMemsetAsync(cur, 0, (size_t)2 * n_nodes * sizeof(int), stream);

    k_wconv<<<(6 * 256 * 128 + 6 * 128 * 128 + 255) / 256, 256, 0, stream>>>(
        W1, W2, Wt1, Wt2);
    k_input<<<((int)nh + 255) / 256, 256, 0, stream>>>(x, Win, bin, h, hb, n_nodes);

    const int eb = (n_edges + 255) / 256;
    k_hist <<<eb, 256, 0, stream>>>(etype, dst, cnt, n_edges, n_nodes);
    k_scan <<<1, 1024, 0, stream>>>(cnt, offs, 2 * n_nodes);
    k_place<<<eb, 256, 0, stream>>>(etype, dst, offs, cur, bucket, n_edges, n_nodes);

    const dim3 mgrid((n_edges + TE - 1) / TE, 2);
    for (int l = 0; l < L; l++) {
        hipMemsetAsync(agg, 0, nh * sizeof(float), stream);
        k_msg<<<mgrid, 256, 0, stream>>>(
            hb, bucket, offs, src, dst,
            Wt1 + (size_t)l * 2 * 128 * 256, b1 + (size_t)l * 2 * H,
            Wt2 + (size_t)l * 2 * 128 * 128, b2 + (size_t)l * 2 * H,
            agg, n_edges, n_nodes);
        k_gru<<<(n_nodes + 15) / 16, 256, 0, stream>>>(
            h, hb, agg,
            Wih + (size_t)l * H * 384, bih + (size_t)l * 384,
            Whh + (size_t)l * H * 384, bhh + (size_t)l * 384,
            n_nodes);
    }

    k_readout<<<(out_size + 7) / 8, 128, 0, stream>>>(
        h, Wr1, br1, Wr2, br2, (float*)d_out, out_size);
}

// Round 4
// 1064.610 us; speedup vs baseline: 10.5836x; 1.7719x over previous
//
#include <hip/hip_runtime.h>
#include <math.h>

// ---------------------------------------------------------------------------
// TannerGNN. Round 4: k_msg rebuilt — weights preloaded to registers in
// MFMA-fragment order, streamed through one 8KB LDS chunk; A-fragments
// gathered direct from global; no sCat. (type,dst)-sorted edges kept.
// N_NODES=50000, N_EDGES=400000, H=128, L=3, T=2, FEAT=4, N_DATA=40000.
// ---------------------------------------------------------------------------

#define H 128
#define TE2 128        // edges per message block (8 waves x 16)
#define MS2 129        // sMsg row stride in f32
#define HS  136        // sHid row stride in bf16 (within wave strip)
#define FEAT 4

typedef __bf16 bf16x8 __attribute__((ext_vector_type(8)));
typedef float  f32x4  __attribute__((ext_vector_type(4)));

// ---------------- input projection: h = relu(x @ W_in + b_in) --------------
__global__ __launch_bounds__(256) void k_input(
    const float* __restrict__ x, const float* __restrict__ Win,
    const float* __restrict__ bin, float* __restrict__ h,
    __bf16* __restrict__ hb, int n_nodes)
{
    int idx = blockIdx.x * 256 + threadIdx.x;
    if (idx >= n_nodes * H) return;
    int n = idx >> 7, j = idx & 127;
    float acc = bin[j];
#pragma unroll
    for (int f = 0; f < FEAT; f++)
        acc += x[n * FEAT + f] * Win[f * H + j];
    float v = fmaxf(acc, 0.f);
    h[idx] = v;
    hb[idx] = (__bf16)v;
}

// ---------------- weight conversion: bf16, MFMA-fragment order -------------
// Per lt (= l*2+t): 12 chunks of 4096 elems. Chunk c (<8): W1 k-range
// [c*32, c*32+32); chunk c (>=8): W2 k-range [(c-8)*32, ...).
// Within chunk: [ct][lane][j]: n = ct*16 + (lane&15), k += (lane>>4)*8 + j.
__global__ __launch_bounds__(256) void k_wconv(
    const float* __restrict__ W1, const float* __restrict__ W2,
    __bf16* __restrict__ Wsw)
{
    int gid = blockIdx.x * 256 + threadIdx.x;
    const int per_lt = 12 * 4096;
    if (gid >= 6 * per_lt) return;
    int lt = gid / per_lt, rem = gid % per_lt;
    int chunk = rem >> 12;
    int within = rem & 4095;
    int ct = within >> 9;
    int lane = (within >> 3) & 63;
    int j = within & 7;
    int r = lane & 15, quad = lane >> 4;
    int n = ct * 16 + r;
    float v;
    if (chunk < 8) {
        int k = chunk * 32 + quad * 8 + j;
        v = W1[((size_t)lt * 256 + k) * 128 + n];
    } else {
        int k = (chunk - 8) * 32 + quad * 8 + j;
        v = W2[((size_t)lt * 128 + k) * 128 + n];
    }
    Wsw[gid] = (__bf16)v;
}

// ---------------- counting sort by key = type*nn + dst ---------------------
__global__ __launch_bounds__(256) void k_hist(
    const int* __restrict__ et, const int* __restrict__ dst,
    int* __restrict__ cnt, int n_edges, int nn)
{
    int i = blockIdx.x * 256 + threadIdx.x;
    if (i < n_edges) atomicAdd(&cnt[et[i] * nn + dst[i]], 1);
}

__global__ __launch_bounds__(1024) void k_scan(
    const int* __restrict__ cnt, int* __restrict__ offs, int n)
{
    __shared__ int sW[16];
    __shared__ int sBase;
    if (threadIdx.x == 0) sBase = 0;
    __syncthreads();
    int lane = threadIdx.x & 63, w = threadIdx.x >> 6;
    for (int c = 0; c < n; c += 1024) {
        int idx = c + threadIdx.x;
        int v = (idx < n) ? cnt[idx] : 0;
        int orig = v;
#pragma unroll
        for (int off = 1; off < 64; off <<= 1) {
            int t = __shfl_up(v, off, 64);
            if (lane >= off) v += t;
        }
        if (lane == 63) sW[w] = v;
        __syncthreads();
        if (w == 0 && lane < 16) {
            int x = sW[lane];
#pragma unroll
            for (int off = 1; off < 16; off <<= 1) {
                int t = __shfl_up(x, off, 64);
                if (lane >= off) x += t;
            }
            sW[lane] = x;
        }
        __syncthreads();
        int wbase = w ? sW[w - 1] : 0;
        int base = sBase;
        if (idx < n) offs[idx] = base + wbase + v - orig;
        __syncthreads();
        if (threadIdx.x == 0) sBase = base + sW[15];
        __syncthreads();
    }
    if (threadIdx.x == 0) offs[n] = sBase;
}

__global__ __launch_bounds__(256) void k_place(
    const int* __restrict__ et, const int* __restrict__ dst,
    const int* __restrict__ offs, int* __restrict__ cur,
    int* __restrict__ bucket, int n_edges, int nn)
{
    int i = blockIdx.x * 256 + threadIdx.x;
    if (i < n_edges) {
        int key = et[i] * nn + dst[i];
        int p = atomicAdd(&cur[key], 1);
        bucket[offs[key] + p] = i;
    }
}

// ---------------- fused MFMA message kernel --------------------------------
// Block = 128 dst-sorted edges of one type, 8 waves; wave w owns 16 edges.
// Weights preloaded to registers (12 x 16B/thread) then streamed through an
// 8KB LDS chunk per K-step. A-fragments gathered direct from global.
__global__ __launch_bounds__(512, 4) void k_msg(
    const __bf16* __restrict__ hb,
    const int* __restrict__ bucket, const int* __restrict__ offs,
    const int* __restrict__ src, const int* __restrict__ dst,
    const __bf16* __restrict__ Wsw, const float* __restrict__ b1l,
    const float* __restrict__ b2l,
    float* __restrict__ agg, int n_edges, int nn)
{
    const int t = blockIdx.y;
    const int c0 = offs[nn];
    const int cnt = t ? (n_edges - c0) : c0;
    const int base = t ? c0 : 0;
    const int start = blockIdx.x * TE2;
    if (start >= cnt) return;

    const __bf16* __restrict__ W = Wsw + (size_t)t * 12 * 4096;
    const float*  __restrict__ b1 = b1l + t * H;
    const float*  __restrict__ b2 = b2l + t * H;

    __shared__ __bf16 sW[4096];            // 8 KB weight chunk
    __shared__ float  sMsg[TE2 * MS2];     // 66048 B; sHid aliases per-wave
    __shared__ int    sDstV[TE2];

    const int tid  = threadIdx.x;
    const int lane = tid & 63;
    const int w    = tid >> 6;
    const int r    = lane & 15;
    const int quad = lane >> 4;

    // ---- preload all 12 weight chunks (coalesced 16 B per thread) ----
    f32x4 wreg[12];
#pragma unroll
    for (int c = 0; c < 12; c++)
        wreg[c] = *(const f32x4*)(W + c * 4096 + tid * 8);

    if (tid < TE2) {
        int i = start + tid;
        sDstV[tid] = (i < cnt) ? dst[bucket[base + i]] : -1;
    }

    // per-lane edge and node pointers
    int ei = start + w * 16 + r;
    int e = bucket[base + (ei < cnt ? ei : cnt - 1)];
    const __bf16* aps = hb + (size_t)src[e] * H;
    const __bf16* apd = hb + (size_t)dst[e] * H;

    // prefetch src-half A fragments
    bf16x8 afS[4];
#pragma unroll
    for (int i = 0; i < 4; i++)
        afS[i] = *(const bf16x8*)(aps + i * 32 + quad * 8);

    __syncthreads();   // sDstV visible (also drains preloads once)

    // ---- Phase A: hid = relu(cat @ W1 + b1), K=256 in 8 chunks ----
    f32x4 acc[8];
#pragma unroll
    for (int ct = 0; ct < 8; ct++) acc[ct] = (f32x4){0.f, 0.f, 0.f, 0.f};

    bf16x8 afD[4];
#pragma unroll
    for (int kc = 0; kc < 8; kc++) {
        __syncthreads();                     // prev chunk fully consumed
        *(f32x4*)(sW + tid * 8) = wreg[kc];
        __syncthreads();
        if (kc == 2) {                       // prefetch dst-half A frags
#pragma unroll
            for (int i = 0; i < 4; i++)
                afD[i] = *(const bf16x8*)(apd + i * 32 + quad * 8);
        }
        bf16x8 a = (kc < 4) ? afS[kc] : afD[kc - 4];
#pragma unroll
        for (int ct = 0; ct < 8; ct++) {
            bf16x8 b = *(const bf16x8*)(sW + ct * 512 + lane * 8);
            acc[ct] = __builtin_amdgcn_mfma_f32_16x16x32_bf16(a, b, acc[ct], 0, 0, 0);
        }
    }

    // epilogue A: bias + relu -> bf16 -> sHid (own-wave strip of sMsg area)
    __bf16* sHid = (__bf16*)(sMsg + w * 16 * MS2);
#pragma unroll
    for (int ct = 0; ct < 8; ct++) {
        int col = ct * 16 + r;
        float bb = b1[col];
#pragma unroll
        for (int g = 0; g < 4; g++) {
            float v = fmaxf(acc[ct][g] + bb, 0.f);
            sHid[(quad * 4 + g) * HS + col] = (__bf16)v;
        }
    }

    // ---- Phase B: msg = hid @ W2 + b2, K=128 in 4 chunks ----
    f32x4 acc2[8];
#pragma unroll
    for (int ct = 0; ct < 8; ct++) acc2[ct] = (f32x4){0.f, 0.f, 0.f, 0.f};
#pragma unroll
    for (int kc = 0; kc < 4; kc++) {
        __syncthreads();
        *(f32x4*)(sW + tid * 8) = wreg[8 + kc];
        __syncthreads();
        bf16x8 a = *(const bf16x8*)(sHid + r * HS + kc * 32 + quad * 8);
#pragma unroll
        for (int ct = 0; ct < 8; ct++) {
            bf16x8 b = *(const bf16x8*)(sW + ct * 512 + lane * 8);
            acc2[ct] = __builtin_amdgcn_mfma_f32_16x16x32_bf16(a, b, acc2[ct], 0, 0, 0);
        }
    }

    // ---- Phase C: msgs (+bias) -> own-wave sMsg rows ----
#pragma unroll
    for (int ct = 0; ct < 8; ct++) {
        int col = ct * 16 + r;
        float bb = b2[col];
#pragma unroll
        for (int g = 0; g < 4; g++)
            sMsg[(w * 16 + quad * 4 + g) * MS2 + col] = acc2[ct][g] + bb;
    }
    __syncthreads();

    // segmented reduction over dst-sorted rows; one atomic per run per col
    {
        int j = tid & 127, strip = tid >> 7;
        int e0 = strip * 32;
        float run = 0.f; int curd = -1;
        for (int q = 0; q < 32; q++) {
            int d = sDstV[e0 + q];
            float v = sMsg[(e0 + q) * MS2 + j];
            if (d != curd) {
                if (curd >= 0) atomicAdd(agg + (size_t)curd * H + j, run);
                run = 0.f; curd = d;
            }
            if (d >= 0) run += v;
        }
        if (curd >= 0) atomicAdd(agg + (size_t)curd * H + j, run);
    }
}

// ---------------- GRU cell (16 nodes per block, in-place h update) ---------
__global__ __launch_bounds__(256) void k_gru(
    float* __restrict__ h, __bf16* __restrict__ hb,
    const float* __restrict__ agg,
    const float* __restrict__ Wih, const float* __restrict__ bih,
    const float* __restrict__ Whh, const float* __restrict__ bhh,
    int n_nodes)
{
    const int nb = blockIdx.x * 16;
    const int tid = threadIdx.x;

    __shared__ float sA[16][H], sH[16][H];
    {
        int e = tid >> 4, q = (tid & 15) * 8;
        int n = nb + e;
        if (n < n_nodes) {
            *(float4*)&sA[e][q]     = *(const float4*)(agg + (size_t)n * H + q);
            *(float4*)&sA[e][q + 4] = *(const float4*)(agg + (size_t)n * H + q + 4);
            *(float4*)&sH[e][q]     = *(const float4*)(h + (size_t)n * H + q);
            *(float4*)&sH[e][q + 4] = *(const float4*)(h + (size_t)n * H + q + 4);
        }
    }
    __syncthreads();

    const int j = tid & 127;
    const int g = tid >> 7;           // 0/1

    float ar[8] = {0,0,0,0,0,0,0,0}, az[8] = {0,0,0,0,0,0,0,0},
          an[8] = {0,0,0,0,0,0,0,0}, gr[8] = {0,0,0,0,0,0,0,0},
          gz[8] = {0,0,0,0,0,0,0,0}, gn[8] = {0,0,0,0,0,0,0,0};

    for (int k = 0; k < H; k++) {
        float wr = Wih[k * 384 + j];
        float wz = Wih[k * 384 + 128 + j];
        float wn = Wih[k * 384 + 256 + j];
        float vr = Whh[k * 384 + j];
        float vz = Whh[k * 384 + 128 + j];
        float vn = Whh[k * 384 + 256 + j];
#pragma unroll
        for (int i = 0; i < 8; i++) {
            int e = g + 2 * i;
            float a = sA[e][k], hh = sH[e][k];
            ar[i] += a * wr;  az[i] += a * wz;  an[i] += a * wn;
            gr[i] += hh * vr; gz[i] += hh * vz; gn[i] += hh * vn;
        }
    }

    float br_ = bih[j], bz_ = bih[128 + j], bn_ = bih[256 + j];
    float cr = bhh[j], cz = bhh[128 + j], cn = bhh[256 + j];
#pragma unroll
    for (int i = 0; i < 8; i++) {
        int e = g + 2 * i;
        int n = nb + e;
        if (n < n_nodes) {
            float rr = 1.f / (1.f + expf(-(ar[i] + br_ + gr[i] + cr)));
            float zz = 1.f / (1.f + expf(-(az[i] + bz_ + gz[i] + cz)));
            float nv = tanhf(an[i] + bn_ + rr * (gn[i] + cn));
            float out = (1.f - zz) * nv + zz * sH[e][j];
            h[(size_t)n * H + j] = out;
            hb[(size_t)n * H + j] = (__bf16)out;
        }
    }
}

// ---------------- readout: out = relu(h@Wr1+br1) @ Wr2 + br2 ---------------
__global__ __launch_bounds__(128) void k_readout(
    const float* __restrict__ h, const float* __restrict__ Wr1,
    const float* __restrict__ br1, const float* __restrict__ Wr2,
    const float* __restrict__ br2, float* __restrict__ out, int n_out)
{
    const int n0 = blockIdx.x * 8;
    const int tid = threadIdx.x;     // 128
    __shared__ float sh[8][H];
    __shared__ float sRed[2][8];
    {
        int e = tid >> 4, q = (tid & 15) * 8;
        int n = n0 + e;
        if (n < n_out) {
            const float* hp = h + (size_t)n * H + q;
            *(float4*)&sh[e][q]     = *(const float4*)hp;
            *(float4*)&sh[e][q + 4] = *(const float4*)(hp + 4);
        }
    }
    __syncthreads();

    const int j = tid;
    float bb = br1[j];
    float acc[8];
#pragma unroll
    for (int e = 0; e < 8; e++) acc[e] = bb;
    for (int k = 0; k < H; k++) {
        float wv = Wr1[k * H + j];
#pragma unroll
        for (int e = 0; e < 8; e++) acc[e] += sh[e][k] * wv;
    }
    float w2 = Wr2[j];
    int lane = tid & 63, w = tid >> 6;
#pragma unroll
    for (int e = 0; e < 8; e++) {
        float val = fmaxf(acc[e], 0.f) * w2;
#pragma unroll
        for (int off = 32; off > 0; off >>= 1)
            val += __shfl_down(val, off, 64);
        if (lane == 0) sRed[w][e] = val;
    }
    __syncthreads();
    if (tid < 8 && n0 + tid < n_out)
        out[n0 + tid] = sRed[0][tid] + sRed[1][tid] + br2[0];
}

// ---------------------------------------------------------------------------
extern "C" void kernel_launch(void* const* d_in, const int* in_sizes, int n_in,
                              void* d_out, int out_size, void* d_ws, size_t ws_size,
                              hipStream_t stream)
{
    const float* x      = (const float*)d_in[0];
    const int*   eidx   = (const int*)d_in[1];
    const int*   etype  = (const int*)d_in[2];
    const float* Win    = (const float*)d_in[4];
    const float* bin    = (const float*)d_in[5];
    const float* W1     = (const float*)d_in[6];   // (3,2,256,128)
    const float* b1     = (const float*)d_in[7];   // (3,2,128)
    const float* W2     = (const float*)d_in[8];   // (3,2,128,128)
    const float* b2     = (const float*)d_in[9];   // (3,2,128)
    const float* Wih    = (const float*)d_in[10];  // (3,128,384)
    const float* bih    = (const float*)d_in[11];  // (3,384)
    const float* Whh    = (const float*)d_in[12];  // (3,128,384)
    const float* bhh    = (const float*)d_in[13];  // (3,384)
    const float* Wr1    = (const float*)d_in[14];
    const float* br1    = (const float*)d_in[15];
    const float* Wr2    = (const float*)d_in[16];
    const float* br2    = (const float*)d_in[17];

    const int n_nodes = in_sizes[0] / FEAT;
    const int n_edges = in_sizes[1] / 2;
    const int L = 3;
    const size_t nh = (size_t)n_nodes * H;

    const int* src = eidx;
    const int* dst = eidx + n_edges;

    // workspace carve-up
    float*  h    = (float*)d_ws;                    // 25.6 MB
    float*  agg  = h + nh;                          // 25.6 MB
    __bf16* hb   = (__bf16*)(agg + nh);             // 12.8 MB
    __bf16* Wsw  = hb + nh;                         // 6*12*4096 bf16
    int* bucket  = (int*)(Wsw + 6 * 12 * 4096);     // n_edges
    int* cnt     = bucket + n_edges;                // 2*nn
    int* cur     = cnt + 2 * n_nodes;               // 2*nn
    int* offs    = cur + 2 * n_nodes;               // 2*nn + 1

    hipMemsetAsync(cnt, 0, (size_t)2 * n_nodes * sizeof(int), stream);
    hipMemsetAsync(cur, 0, (size_t)2 * n_nodes * sizeof(int), stream);

    k_wconv<<<(6 * 12 * 4096 + 255) / 256, 256, 0, stream>>>(W1, W2, Wsw);
    k_input<<<((int)nh + 255) / 256, 256, 0, stream>>>(x, Win, bin, h, hb, n_nodes);

    const int eb = (n_edges + 255) / 256;
    k_hist <<<eb, 256, 0, stream>>>(etype, dst, cnt, n_edges, n_nodes);
    k_scan <<<1, 1024, 0, stream>>>(cnt, offs, 2 * n_nodes);
    k_place<<<eb, 256, 0, stream>>>(etype, dst, offs, cur, bucket, n_edges, n_nodes);

    const dim3 mgrid((n_edges + TE2 - 1) / TE2, 2);
    for (int l = 0; l < L; l++) {
        hipMemsetAsync(agg, 0, nh * sizeof(float), stream);
        k_msg<<<mgrid, 512, 0, stream>>>(
            hb, bucket, offs, src, dst,
            Wsw + (size_t)l * 2 * 12 * 4096,
            b1 + (size_t)l * 2 * H, b2 + (size_t)l * 2 * H,
            agg, n_edges, n_nodes);
        k_gru<<<(n_nodes + 15) / 16, 256, 0, stream>>>(
            h, hb, agg,
            Wih + (size_t)l * H * 384, bih + (size_t)l * 384,
            Whh + (size_t)l * H * 384, bhh + (size_t)l * 384,
            n_nodes);
    }

    k_readout<<<(out_size + 7) / 8, 128, 0, stream>>>(
        h, Wr1, br1, Wr2, br2, (float*)d_out, out_size);
}